// Round 18
// baseline (137.494 us; speedup 1.0000x reference)
//
#include <hip/hip_runtime.h>

typedef _Float16 f16;
typedef _Float16 f16x4 __attribute__((ext_vector_type(4)));
typedef _Float16 f16x8 __attribute__((ext_vector_type(8)));
typedef float f32x4 __attribute__((ext_vector_type(4)));

// async global->LDS, 16B per lane; LDS dest = wave-uniform base + lane*16
#define LOADLDS16(gp, lp)                                                     \
  __builtin_amdgcn_global_load_lds(                                           \
      (const __attribute__((address_space(1))) void*)(gp),                    \
      (__attribute__((address_space(3))) void*)(lp), 16, 0, 0)

// ---------------------------------------------------------------------------
// Merged prep: blocks 0-8191 cast activations f32->f16 (float4 vectorized);
// blocks 8192-9215 cast+transpose the 4 weight matrices (64x64 LDS tiles).
// ---------------------------------------------------------------------------
__global__ __launch_bounds__(256) void k_prep(
    const float* __restrict__ xa, const float* __restrict__ xb,
    f16* __restrict__ ya, f16* __restrict__ yb, const float* __restrict__ w0,
    const float* __restrict__ w1, const float* __restrict__ w2,
    const float* __restrict__ w3, f16* __restrict__ o0, f16* __restrict__ o1,
    f16* __restrict__ o2, f16* __restrict__ o3) {
  __shared__ f16 T[64][72];
  const int tid = threadIdx.x;
  const int bid = blockIdx.x;
  if (bid < 8192) {
    int i = bid * 256 + tid;
    const float* x;
    f16* y;
    if (i < 1048576) {
      x = xa; y = ya;
    } else {
      x = xb; y = yb; i -= 1048576;
    }
    float4 v = reinterpret_cast<const float4*>(x)[i];
    f16x4 o;
    o[0] = (f16)v.x; o[1] = (f16)v.y; o[2] = (f16)v.z; o[3] = (f16)v.w;
    reinterpret_cast<f16x4*>(y)[i] = o;
    return;
  }
  const int bid2 = bid - 8192;
  const int z = bid2 >> 8, yb_ = (bid2 >> 4) & 15, xb_ = bid2 & 15;
  const float* W;
  f16* O;
  switch (z) {
    case 0: W = w0; O = o0; break;
    case 1: W = w1; O = o1; break;
    case 2: W = w2; O = o2; break;
    default: W = w3; O = o3; break;
  }
  const int r0 = yb_ * 64, c0 = xb_ * 64;
#pragma unroll
  for (int i = 0; i < 4; ++i) {
    int c = i * 256 + tid;
    int row = c >> 4, col = (c & 15) * 4;
    float4 v = *reinterpret_cast<const float4*>(W + (size_t)(r0 + row) * 1024 + c0 + col);
    T[col + 0][row] = (f16)v.x;
    T[col + 1][row] = (f16)v.y;
    T[col + 2][row] = (f16)v.z;
    T[col + 3][row] = (f16)v.w;
  }
  __syncthreads();
#pragma unroll
  for (int i = 0; i < 2; ++i) {
    int c = i * 256 + tid;
    int cc = c >> 3, ro = (c & 7) * 8;
    f16x8 v;
#pragma unroll
    for (int j = 0; j < 8; ++j) v[j] = T[cc][ro + j];
    *reinterpret_cast<f16x8*>(O + (size_t)(c0 + cc) * 1024 + r0 + ro) = v;
  }
}

// ---------------------------------------------------------------------------
// Fused QKV projection: C[4096, 3072], cols 0-1023 = Xq@Wqt, 1024-2047 =
// Xkv@Wkt, 2048-3071 = Xkv@Wvt. m97 structure: BM=BN=128, BK=64, 4 waves.
// v18: (1) XCD-chunked block swizzle (768 = 8 x 96, bijective);
//      (2) Q/K planes computed as C^T via SWAPPED mfma operands -> each lane
//          holds 4 consecutive dh per fragment -> 16 aligned f16x4 stores
//          (was 64 scalar b16 stores). V plane keeps normal orientation
//          (its [bh][dh][s] store needs 4 consecutive s per lane).
// ---------------------------------------------------------------------------
__global__ __launch_bounds__(256) void k_gemm_qkv(const f16* __restrict__ Xq,
                                                  const f16* __restrict__ Xkv,
                                                  const f16* __restrict__ Bt,
                                                  f16* __restrict__ outp) {
  __shared__ f16 As[128 * 64];  // 16 KB
  __shared__ f16 Bs[128 * 64];  // 16 KB
  const int tid = threadIdx.x;
  const int w = tid >> 6, l = tid & 63;
  const int lr = l & 15, lq = l >> 4;
  // XCD-chunked swizzle: flat 0..767 -> each XCD gets 96 contiguous ords
  const int flat = blockIdx.y * 24 + blockIdx.x;
  const int ord = (flat & 7) * 96 + (flat >> 3);
  const int m0 = (ord / 24) * 128, n0 = (ord % 24) * 128;
  const f16* A = (n0 < 1024) ? Xq : Xkv;
  const int wr = (w >> 1) * 64, wc = (w & 1) * 64;
  const int K = 1024;
  const bool vplane = (n0 >= 2048);
  f32x4 acc[4][4] = {};
  for (int kt = 0; kt < K; kt += 64) {
#pragma unroll
    for (int i = 0; i < 4; ++i) {
      int c = (i * 4 + w) * 64 + l;
      LOADLDS16(A + (size_t)(m0 + (c >> 3)) * K + kt + (c & 7) * 8,
                As + (size_t)(i * 4 + w) * 512);
      LOADLDS16(Bt + (size_t)(n0 + (c >> 3)) * K + kt + (c & 7) * 8,
                Bs + (size_t)(i * 4 + w) * 512);
    }
    __syncthreads();
#pragma unroll
    for (int kk = 0; kk < 2; ++kk) {
      f16x8 af[4], bf[4];
#pragma unroll
      for (int m = 0; m < 4; ++m)
        af[m] = *reinterpret_cast<const f16x8*>(As + (wr + m * 16 + lr) * 64 + kk * 32 + lq * 8);
#pragma unroll
      for (int n = 0; n < 4; ++n)
        bf[n] = *reinterpret_cast<const f16x8*>(Bs + (wc + n * 16 + lr) * 64 + kk * 32 + lq * 8);
      if (vplane) {
#pragma unroll
        for (int m = 0; m < 4; ++m)
#pragma unroll
          for (int n = 0; n < 4; ++n)
            acc[m][n] = __builtin_amdgcn_mfma_f32_16x16x32_f16(af[m], bf[n], acc[m][n], 0, 0, 0);
      } else {
        // swapped: acc[m][n][r] = C[col = n-dim + lq*4+r][row = m-dim + lr]
#pragma unroll
        for (int m = 0; m < 4; ++m)
#pragma unroll
          for (int n = 0; n < 4; ++n)
            acc[m][n] = __builtin_amdgcn_mfma_f32_16x16x32_f16(bf[n], af[m], acc[m][n], 0, 0, 0);
      }
    }
    __syncthreads();
  }
  if (vplane) {
    // V transposed: vtb[bh][dh][s], 4 consecutive s per lane = f16x4 store
#pragma unroll
    for (int m = 0; m < 4; ++m)
#pragma unroll
      for (int n = 0; n < 4; ++n) {
        int col = n0 + wc + n * 16 + lr;
        int row0 = m0 + wr + m * 16 + lq * 4;
        int b = row0 >> 10, s0 = row0 & 1023;
        int cc = col & 1023;
        int h = cc >> 6, dh = cc & 63;
        f16x4 v4;
#pragma unroll
        for (int r = 0; r < 4; ++r) v4[r] = (f16)acc[m][n][r];
        *reinterpret_cast<f16x4*>(
            outp + (size_t)2 * 4194304 +
            ((size_t)(b * 16 + h)) * 65536 + (size_t)dh * 1024 + s0) = v4;
      }
  } else {
    // Q/K planes (swapped acc): 4 consecutive dh per lane = f16x4 store
#pragma unroll
    for (int m = 0; m < 4; ++m)
#pragma unroll
      for (int n = 0; n < 4; ++n) {
        int row0 = m0 + wr + m * 16 + lr;       // s-dim
        int col0 = n0 + wc + n * 16 + lq * 4;   // dh-dim (4 consecutive)
        int b = row0 >> 10, sidx = row0 & 1023;
        int plane = col0 >> 10, cc = col0 & 1023;
        int h = cc >> 6, dh0 = cc & 63;
        f16x4 v4;
#pragma unroll
        for (int r = 0; r < 4; ++r) v4[r] = (f16)acc[m][n][r];
        *reinterpret_cast<f16x4*>(
            outp + (size_t)plane * 4194304 +
            (((size_t)(b * 16 + h)) * 1024 + sidx) * 64 + dh0) = v4;
      }
  }
}

// ---------------------------------------------------------------------------
// Output GEMM: C[M,N] f32 = A[M,K] @ Bt[N,K]^T. BM=64, BN=128 (512 blocks).
// v18: XCD-chunked block swizzle (512 = 8 x 64).
// ---------------------------------------------------------------------------
__global__ __launch_bounds__(256) void k_gemm_o(const f16* __restrict__ A,
                                                const f16* __restrict__ Bt,
                                                float* __restrict__ out, int M,
                                                int N, int K) {
  __shared__ f16 As[64 * 64];
  __shared__ f16 Bs[128 * 64];
  const int tid = threadIdx.x;
  const int w = tid >> 6, l = tid & 63;
  const int lr = l & 15, lq = l >> 4;
  const int flat = blockIdx.y * 8 + blockIdx.x;
  const int ord = (flat & 7) * 64 + (flat >> 3);
  const int m0 = (ord >> 3) * 64, n0 = (ord & 7) * 128;
  const int wr = (w >> 1) * 32, wc = (w & 1) * 64;
  f32x4 acc[2][4] = {};
  for (int kt = 0; kt < K; kt += 64) {
#pragma unroll
    for (int i = 0; i < 2; ++i) {
      int c = (i * 4 + w) * 64 + l;
      LOADLDS16(A + (size_t)(m0 + (c >> 3)) * K + kt + (c & 7) * 8,
                As + (size_t)(i * 4 + w) * 512);
    }
#pragma unroll
    for (int i = 0; i < 4; ++i) {
      int c = (i * 4 + w) * 64 + l;
      LOADLDS16(Bt + (size_t)(n0 + (c >> 3)) * K + kt + (c & 7) * 8,
                Bs + (size_t)(i * 4 + w) * 512);
    }
    __syncthreads();
#pragma unroll
    for (int kk = 0; kk < 2; ++kk) {
      f16x8 af[2], bf[4];
#pragma unroll
      for (int m = 0; m < 2; ++m)
        af[m] = *reinterpret_cast<const f16x8*>(As + (wr + m * 16 + lr) * 64 + kk * 32 + lq * 8);
#pragma unroll
      for (int n = 0; n < 4; ++n)
        bf[n] = *reinterpret_cast<const f16x8*>(Bs + (wc + n * 16 + lr) * 64 + kk * 32 + lq * 8);
#pragma unroll
      for (int m = 0; m < 2; ++m)
#pragma unroll
        for (int n = 0; n < 4; ++n)
          acc[m][n] = __builtin_amdgcn_mfma_f32_16x16x32_f16(af[m], bf[n], acc[m][n], 0, 0, 0);
    }
    __syncthreads();
  }
#pragma unroll
  for (int m = 0; m < 2; ++m)
#pragma unroll
    for (int n = 0; n < 4; ++n)
#pragma unroll
      for (int r = 0; r < 4; ++r) {
        int row = m0 + wr + m * 16 + lq * 4 + r;
        int col = n0 + wc + n * 16 + lr;
        out[(size_t)row * N + col] = acc[m][n][r];
      }
}

// ---------------------------------------------------------------------------
// Fused flash attention (T5: scores = QK^T + bias, no 1/sqrt scale).
// FROZEN at round-17 v16 (~66 us; 9 structural variants all land 65-70 ->
// LDS-issue + period-latency floor for this 4-wave/16-period structure).
// ---------------------------------------------------------------------------
__global__ __launch_bounds__(256) void k_attn(const f16* __restrict__ qb,
                                              const f16* __restrict__ kb,
                                              const f16* __restrict__ vtb,
                                              const float* __restrict__ bias,
                                              f16* __restrict__ ctx) {
  const int bid = blockIdx.x;
  const int ord = (bid & 7) * 128 + (bid >> 3);  // XCD-chunked
  const int h = ord >> 6, b = (ord >> 4) & 3, qt = ord & 15;  // qt innermost
  const int bh = b * 16 + h;
  const int q0 = qt * 64;
  const int tid = threadIdx.x, w = tid >> 6, l = tid & 63;
  const int lr = l & 15, lq = l >> 4;

  __shared__ f16 Kb[2][4096];  // [kv=64][dh=64], granule swz g^(row&7)
  __shared__ f16 Vb[2][4096];  // [dh=64][kv=64], granule swz g^(row&7)

  const f16* qp = qb + ((size_t)bh * 1024 + q0 + w * 16 + lr) * 64 + lq * 8;
  f16x8 qf0 = *reinterpret_cast<const f16x8*>(qp);
  f16x8 qf1 = *reinterpret_cast<const f16x8*>(qp + 32);

  f32x4 O[4] = {};
  float mrun = -3.0e38f, rsum = 0.f;  // per-lane; q-row = lr

  const f16* kbase = kb + (size_t)bh * 65536;
  const f16* vbase = vtb + (size_t)bh * 65536;
  const float* bq = bias + ((size_t)h * 1024 + q0 + w * 16 + lr) * 1024 + lq * 4;

  auto stage = [&](int t, int nxt) {
#pragma unroll
    for (int i = 0; i < 2; ++i) {
      int c = (i * 4 + w) * 64 + l;
      int row = c >> 3, g = (c & 7) ^ (row & 7);
      LOADLDS16(kbase + (size_t)(t * 64 + row) * 64 + g * 8,
                &Kb[nxt][(i * 4 + w) * 512]);
      LOADLDS16(vbase + (size_t)row * 1024 + t * 64 + g * 8,
                &Vb[nxt][(i * 4 + w) * 512]);
    }
  };

  stage(0, 0);

#pragma unroll 1
  for (int t = 0; t < 16; ++t) {
    const int cur = t & 1;
    __builtin_amdgcn_s_barrier();
    f32x4 bf[4];
#pragma unroll
    for (int c = 0; c < 4; ++c)
      bf[c] = *reinterpret_cast<const f32x4*>(bq + t * 64 + c * 16);
    __builtin_amdgcn_sched_barrier(0);
    if (t < 15) stage(t + 1, cur ^ 1);
    __builtin_amdgcn_sched_barrier(0);
    if (t < 15) {
      asm volatile("s_waitcnt vmcnt(8)" ::: "memory");
    } else {
      asm volatile("s_waitcnt vmcnt(4)" ::: "memory");
    }
    __builtin_amdgcn_sched_barrier(0);

    f32x4 S[4] = {};
    __builtin_amdgcn_s_setprio(1);
#pragma unroll
    for (int c = 0; c < 4; ++c) {
      int row = c * 16 + lr;
      const f16* kbp = &Kb[cur][row * 64];
      f16x8 kf0 = *reinterpret_cast<const f16x8*>(kbp + ((lq ^ (row & 7)) * 8));
      f16x8 kf1 = *reinterpret_cast<const f16x8*>(kbp + (((4 + lq) ^ (row & 7)) * 8));
      S[c] = __builtin_amdgcn_mfma_f32_16x16x32_f16(kf0, qf0, S[c], 0, 0, 0);
      S[c] = __builtin_amdgcn_mfma_f32_16x16x32_f16(kf1, qf1, S[c], 0, 0, 0);
    }
    __builtin_amdgcn_s_setprio(0);

#pragma unroll
    for (int c = 0; c < 4; ++c)
#pragma unroll
      for (int r = 0; r < 4; ++r) S[c][r] += bf[c][r];

    float tmax = fmaxf(
        fmaxf(fmaxf(fmaxf(S[0][0], S[0][1]), fmaxf(S[0][2], S[0][3])),
              fmaxf(fmaxf(S[1][0], S[1][1]), fmaxf(S[1][2], S[1][3]))),
        fmaxf(fmaxf(fmaxf(S[2][0], S[2][1]), fmaxf(S[2][2], S[2][3])),
              fmaxf(fmaxf(S[3][0], S[3][1]), fmaxf(S[3][2], S[3][3]))));
    if (!__all(tmax <= mrun + 8.0f)) {
      tmax = fmaxf(tmax, __shfl_xor(tmax, 16, 64));
      tmax = fmaxf(tmax, __shfl_xor(tmax, 32, 64));
      float mnew = fmaxf(mrun, tmax);
      float sc = __expf(mrun - mnew);
      mrun = mnew;
      rsum *= sc;
      int sb = l & 48;
#pragma unroll
      for (int r = 0; r < 4; ++r) {
        float scO = __shfl(sc, sb | (lq * 4 + r), 64);
#pragma unroll
        for (int c = 0; c < 4; ++c) O[c][r] *= scO;
      }
    }

    f32x4 p[4];
#pragma unroll
    for (int c = 0; c < 4; ++c) {
#pragma unroll
      for (int r = 0; r < 4; ++r) p[c][r] = __expf(S[c][r] - mrun);
      rsum += (p[c][0] + p[c][1]) + (p[c][2] + p[c][3]);
    }
    f16x8 pa0, pa1;
#pragma unroll
    for (int j = 0; j < 4; ++j) {
      pa0[j] = (f16)p[0][j];
      pa0[4 + j] = (f16)p[1][j];
      pa1[j] = (f16)p[2][j];
      pa1[4 + j] = (f16)p[3][j];
    }

    __builtin_amdgcn_s_setprio(1);
#pragma unroll
    for (int c = 0; c < 4; ++c) {
      int row = c * 16 + lr;
      const f16* vbp = &Vb[cur][row * 64];
      int s8 = row & 7, sub = (lq & 1) * 4, gh = lq >> 1;
      f16x4 v0 = *reinterpret_cast<const f16x4*>(vbp + ((gh ^ s8) * 8 + sub));
      f16x4 v1 = *reinterpret_cast<const f16x4*>(vbp + (((2 + gh) ^ s8) * 8 + sub));
      f16x4 v2 = *reinterpret_cast<const f16x4*>(vbp + (((4 + gh) ^ s8) * 8 + sub));
      f16x4 v3 = *reinterpret_cast<const f16x4*>(vbp + (((6 + gh) ^ s8) * 8 + sub));
      f16x8 vf0, vf1;
#pragma unroll
      for (int j = 0; j < 4; ++j) {
        vf0[j] = v0[j];
        vf0[4 + j] = v1[j];
        vf1[j] = v2[j];
        vf1[4 + j] = v3[j];
      }
      O[c] = __builtin_amdgcn_mfma_f32_16x16x32_f16(pa0, vf0, O[c], 0, 0, 0);
      O[c] = __builtin_amdgcn_mfma_f32_16x16x32_f16(pa1, vf1, O[c], 0, 0, 0);
    }
    __builtin_amdgcn_s_setprio(0);
    __builtin_amdgcn_sched_barrier(0);
  }

  rsum += __shfl_xor(rsum, 16, 64);
  rsum += __shfl_xor(rsum, 32, 64);
  int sb = l & 48;
  float rs[4];
#pragma unroll
  for (int r = 0; r < 4; ++r) rs[r] = __shfl(rsum, sb | (lq * 4 + r), 64);

#pragma unroll
  for (int c = 0; c < 4; ++c)
#pragma unroll
    for (int r = 0; r < 4; ++r) {
      float o = O[c][r] / rs[r];
      int row = q0 + w * 16 + lq * 4 + r;
      ctx[((size_t)b * 1024 + row) * 1024 + h * 64 + c * 16 + lr] = (f16)o;
    }
}

// ---------------------------------------------------------------------------
extern "C" void kernel_launch(void* const* d_in, const int* in_sizes, int n_in,
                              void* d_out, int out_size, void* d_ws,
                              size_t ws_size, hipStream_t stream) {
  const float* input_ids = (const float*)d_in[0];
  const float* enc = (const float*)d_in[1];
  const float* bias = (const float*)d_in[2];
  const float* Wq = (const float*)d_in[3];
  const float* Wk = (const float*)d_in[4];
  const float* Wv = (const float*)d_in[5];
  const float* Wo = (const float*)d_in[6];

  char* ws = (char*)d_ws;
  const size_t MB = 1024 * 1024;
  f16* Xq  = (f16*)(ws + 0 * MB);   // 8 MB; dead after QKV-proj -> reused as ctx
  f16* Xkv = (f16*)(ws + 8 * MB);   // 8 MB (GEMM A input)
  f16* Wqt = (f16*)(ws + 16 * MB);  // 2 MB each; Wqt|Wkt|Wvt contiguous = [3072][1024]
  f16* Wkt = (f16*)(ws + 18 * MB);
  f16* Wvt = (f16*)(ws + 20 * MB);
  f16* Wot = (f16*)(ws + 22 * MB);
  f16* qbuf = (f16*)(ws + 24 * MB); // 8 MB [bh][s][dh]; kbuf plane follows;
  f16* kbuf = (f16*)(ws + 32 * MB); // plane 2 = vtb [bh][dh][s] (transposed in epi)
  f16* vtb  = (f16*)(ws + 40 * MB);
  f16* ctxb = Xq;   // [4096][1024]

  // merged cast + weight-transpose prep (one launch)
  k_prep<<<9216, 256, 0, stream>>>(input_ids, enc, Xq, Xkv, Wq, Wk, Wv, Wo,
                                   Wqt, Wkt, Wvt, Wot);

  // fused Q+K+V projection (Q/K planes swapped-operand, V transposed in epi)
  k_gemm_qkv<<<dim3(24, 32), 256, 0, stream>>>(Xq, Xkv, Wqt, qbuf);

  k_attn<<<1024, 256, 0, stream>>>(qbuf, kbuf, vtb, bias, ctxb);

  k_gemm_o<<<dim3(8, 64), 256, 0, stream>>>(ctxb, Wot, (float*)d_out, 4096, 1024, 1024);
}

// Round 19
// 137.054 us; speedup vs baseline: 1.0032x; 1.0032x over previous
//
#include <hip/hip_runtime.h>

typedef _Float16 f16;
typedef _Float16 f16x4 __attribute__((ext_vector_type(4)));
typedef _Float16 f16x8 __attribute__((ext_vector_type(8)));
typedef float f32x4 __attribute__((ext_vector_type(4)));
typedef float f32x16 __attribute__((ext_vector_type(16)));

// async global->LDS, 16B per lane; LDS dest = wave-uniform base + lane*16
#define LOADLDS16(gp, lp)                                                     \
  __builtin_amdgcn_global_load_lds(                                           \
      (const __attribute__((address_space(1))) void*)(gp),                    \
      (__attribute__((address_space(3))) void*)(lp), 16, 0, 0)

// ---------------------------------------------------------------------------
// Merged prep: blocks 0-8191 cast activations f32->f16 (float4 vectorized);
// blocks 8192-9215 cast+transpose the 4 weight matrices (64x64 LDS tiles).
// ---------------------------------------------------------------------------
__global__ __launch_bounds__(256) void k_prep(
    const float* __restrict__ xa, const float* __restrict__ xb,
    f16* __restrict__ ya, f16* __restrict__ yb, const float* __restrict__ w0,
    const float* __restrict__ w1, const float* __restrict__ w2,
    const float* __restrict__ w3, f16* __restrict__ o0, f16* __restrict__ o1,
    f16* __restrict__ o2, f16* __restrict__ o3) {
  __shared__ f16 T[64][72];
  const int tid = threadIdx.x;
  const int bid = blockIdx.x;
  if (bid < 8192) {
    int i = bid * 256 + tid;
    const float* x;
    f16* y;
    if (i < 1048576) {
      x = xa; y = ya;
    } else {
      x = xb; y = yb; i -= 1048576;
    }
    float4 v = reinterpret_cast<const float4*>(x)[i];
    f16x4 o;
    o[0] = (f16)v.x; o[1] = (f16)v.y; o[2] = (f16)v.z; o[3] = (f16)v.w;
    reinterpret_cast<f16x4*>(y)[i] = o;
    return;
  }
  const int bid2 = bid - 8192;
  const int z = bid2 >> 8, yb_ = (bid2 >> 4) & 15, xb_ = bid2 & 15;
  const float* W;
  f16* O;
  switch (z) {
    case 0: W = w0; O = o0; break;
    case 1: W = w1; O = o1; break;
    case 2: W = w2; O = o2; break;
    default: W = w3; O = o3; break;
  }
  const int r0 = yb_ * 64, c0 = xb_ * 64;
#pragma unroll
  for (int i = 0; i < 4; ++i) {
    int c = i * 256 + tid;
    int row = c >> 4, col = (c & 15) * 4;
    float4 v = *reinterpret_cast<const float4*>(W + (size_t)(r0 + row) * 1024 + c0 + col);
    T[col + 0][row] = (f16)v.x;
    T[col + 1][row] = (f16)v.y;
    T[col + 2][row] = (f16)v.z;
    T[col + 3][row] = (f16)v.w;
  }
  __syncthreads();
#pragma unroll
  for (int i = 0; i < 2; ++i) {
    int c = i * 256 + tid;
    int cc = c >> 3, ro = (c & 7) * 8;
    f16x8 v;
#pragma unroll
    for (int j = 0; j < 8; ++j) v[j] = T[cc][ro + j];
    *reinterpret_cast<f16x8*>(O + (size_t)(c0 + cc) * 1024 + r0 + ro) = v;
  }
}

// ---------------------------------------------------------------------------
// Fused QKV projection (round-18 v18, frozen): swizzled grid, swapped-operand
// Q/K epilogue (f16x4 stores), V written transposed.
// ---------------------------------------------------------------------------
__global__ __launch_bounds__(256) void k_gemm_qkv(const f16* __restrict__ Xq,
                                                  const f16* __restrict__ Xkv,
                                                  const f16* __restrict__ Bt,
                                                  f16* __restrict__ outp) {
  __shared__ f16 As[128 * 64];  // 16 KB
  __shared__ f16 Bs[128 * 64];  // 16 KB
  const int tid = threadIdx.x;
  const int w = tid >> 6, l = tid & 63;
  const int lr = l & 15, lq = l >> 4;
  const int flat = blockIdx.y * 24 + blockIdx.x;
  const int ord = (flat & 7) * 96 + (flat >> 3);
  const int m0 = (ord / 24) * 128, n0 = (ord % 24) * 128;
  const f16* A = (n0 < 1024) ? Xq : Xkv;
  const int wr = (w >> 1) * 64, wc = (w & 1) * 64;
  const int K = 1024;
  const bool vplane = (n0 >= 2048);
  f32x4 acc[4][4] = {};
  for (int kt = 0; kt < K; kt += 64) {
#pragma unroll
    for (int i = 0; i < 4; ++i) {
      int c = (i * 4 + w) * 64 + l;
      LOADLDS16(A + (size_t)(m0 + (c >> 3)) * K + kt + (c & 7) * 8,
                As + (size_t)(i * 4 + w) * 512);
      LOADLDS16(Bt + (size_t)(n0 + (c >> 3)) * K + kt + (c & 7) * 8,
                Bs + (size_t)(i * 4 + w) * 512);
    }
    __syncthreads();
#pragma unroll
    for (int kk = 0; kk < 2; ++kk) {
      f16x8 af[4], bf[4];
#pragma unroll
      for (int m = 0; m < 4; ++m)
        af[m] = *reinterpret_cast<const f16x8*>(As + (wr + m * 16 + lr) * 64 + kk * 32 + lq * 8);
#pragma unroll
      for (int n = 0; n < 4; ++n)
        bf[n] = *reinterpret_cast<const f16x8*>(Bs + (wc + n * 16 + lr) * 64 + kk * 32 + lq * 8);
      if (vplane) {
#pragma unroll
        for (int m = 0; m < 4; ++m)
#pragma unroll
          for (int n = 0; n < 4; ++n)
            acc[m][n] = __builtin_amdgcn_mfma_f32_16x16x32_f16(af[m], bf[n], acc[m][n], 0, 0, 0);
      } else {
#pragma unroll
        for (int m = 0; m < 4; ++m)
#pragma unroll
          for (int n = 0; n < 4; ++n)
            acc[m][n] = __builtin_amdgcn_mfma_f32_16x16x32_f16(bf[n], af[m], acc[m][n], 0, 0, 0);
      }
    }
    __syncthreads();
  }
  if (vplane) {
#pragma unroll
    for (int m = 0; m < 4; ++m)
#pragma unroll
      for (int n = 0; n < 4; ++n) {
        int col = n0 + wc + n * 16 + lr;
        int row0 = m0 + wr + m * 16 + lq * 4;
        int b = row0 >> 10, s0 = row0 & 1023;
        int cc = col & 1023;
        int h = cc >> 6, dh = cc & 63;
        f16x4 v4;
#pragma unroll
        for (int r = 0; r < 4; ++r) v4[r] = (f16)acc[m][n][r];
        *reinterpret_cast<f16x4*>(
            outp + (size_t)2 * 4194304 +
            ((size_t)(b * 16 + h)) * 65536 + (size_t)dh * 1024 + s0) = v4;
      }
  } else {
#pragma unroll
    for (int m = 0; m < 4; ++m)
#pragma unroll
      for (int n = 0; n < 4; ++n) {
        int row0 = m0 + wr + m * 16 + lr;
        int col0 = n0 + wc + n * 16 + lq * 4;
        int b = row0 >> 10, sidx = row0 & 1023;
        int plane = col0 >> 10, cc = col0 & 1023;
        int h = cc >> 6, dh0 = cc & 63;
        f16x4 v4;
#pragma unroll
        for (int r = 0; r < 4; ++r) v4[r] = (f16)acc[m][n][r];
        *reinterpret_cast<f16x4*>(
            outp + (size_t)plane * 4194304 +
            (((size_t)(b * 16 + h)) * 1024 + sidx) * 64 + dh0) = v4;
      }
  }
}

// ---------------------------------------------------------------------------
// Output GEMM (round-18 v18, frozen): swizzled grid, BM=64 BN=128.
// ---------------------------------------------------------------------------
__global__ __launch_bounds__(256) void k_gemm_o(const f16* __restrict__ A,
                                                const f16* __restrict__ Bt,
                                                float* __restrict__ out, int M,
                                                int N, int K) {
  __shared__ f16 As[64 * 64];
  __shared__ f16 Bs[128 * 64];
  const int tid = threadIdx.x;
  const int w = tid >> 6, l = tid & 63;
  const int lr = l & 15, lq = l >> 4;
  const int flat = blockIdx.y * 8 + blockIdx.x;
  const int ord = (flat & 7) * 64 + (flat >> 3);
  const int m0 = (ord >> 3) * 64, n0 = (ord & 7) * 128;
  const int wr = (w >> 1) * 32, wc = (w & 1) * 64;
  f32x4 acc[2][4] = {};
  for (int kt = 0; kt < K; kt += 64) {
#pragma unroll
    for (int i = 0; i < 2; ++i) {
      int c = (i * 4 + w) * 64 + l;
      LOADLDS16(A + (size_t)(m0 + (c >> 3)) * K + kt + (c & 7) * 8,
                As + (size_t)(i * 4 + w) * 512);
    }
#pragma unroll
    for (int i = 0; i < 4; ++i) {
      int c = (i * 4 + w) * 64 + l;
      LOADLDS16(Bt + (size_t)(n0 + (c >> 3)) * K + kt + (c & 7) * 8,
                Bs + (size_t)(i * 4 + w) * 512);
    }
    __syncthreads();
#pragma unroll
    for (int kk = 0; kk < 2; ++kk) {
      f16x8 af[2], bf[4];
#pragma unroll
      for (int m = 0; m < 2; ++m)
        af[m] = *reinterpret_cast<const f16x8*>(As + (wr + m * 16 + lr) * 64 + kk * 32 + lq * 8);
#pragma unroll
      for (int n = 0; n < 4; ++n)
        bf[n] = *reinterpret_cast<const f16x8*>(Bs + (wc + n * 16 + lr) * 64 + kk * 32 + lq * 8);
#pragma unroll
      for (int m = 0; m < 2; ++m)
#pragma unroll
        for (int n = 0; n < 4; ++n)
          acc[m][n] = __builtin_amdgcn_mfma_f32_16x16x32_f16(af[m], bf[n], acc[m][n], 0, 0, 0);
    }
    __syncthreads();
  }
#pragma unroll
  for (int m = 0; m < 2; ++m)
#pragma unroll
    for (int n = 0; n < 4; ++n)
#pragma unroll
      for (int r = 0; r < 4; ++r) {
        int row = m0 + wr + m * 16 + lq * 4 + r;
        int col = n0 + wc + n * 16 + lr;
        out[(size_t)row * N + col] = acc[m][n][r];
      }
}

// ---------------------------------------------------------------------------
// Fused flash attention (T5), v19: 32x32x16 MFMA core.
// 4 waves x 32 q-rows (QBLK=128), KVBLK=64, grid 512 (2 blocks/CU).
// Mechanism: same K/V LDS bytes feed 2x q-rows and each 32x32 MFMA moves 2x
// FLOP per b128 fragment read -> ~4x less LDS-read pressure per FLOP (the
// diagnosed wall of the 16x16 structure). Skeleton (staging, swizzle,
// barrier + counted vmcnt, defer-max) identical to v16.
// Layouts: C/D col=lane&31,row=(reg&3)+8(reg>>2)+4(lane>>5) [guide-verified];
// A/B row=lane&31,k=(lane>>5)*8+j [analogous to the verified 16x16 pattern].
// Swapped QK: S^T = mfma(K,Q,bias) -> lane holds 32 S-values of ONE q-row.
// In-reg P for PV: 4 quad-exchanges with lane^32 via __shfl_xor (T12 shfl
// form); B-frag pb[u] = [own|recv] per half. PV: O^T = mfma(V^T, P^T).
// ---------------------------------------------------------------------------
__global__ __launch_bounds__(256, 2) void k_attn(const f16* __restrict__ qb,
                                                 const f16* __restrict__ kb,
                                                 const f16* __restrict__ vtb,
                                                 const float* __restrict__ bias,
                                                 f16* __restrict__ ctx) {
  const int bid = blockIdx.x;
  const int ord = (bid & 7) * 64 + (bid >> 3);  // XCD-chunked: 2 heads/XCD
  const int h = ord >> 5, b = (ord >> 3) & 3, qt = ord & 7;  // qt innermost
  const int bh = b * 16 + h;
  const int q0 = qt * 128;
  const int tid = threadIdx.x, w = tid >> 6, l = tid & 63;
  const int l31 = l & 31, xi = l >> 5;
  const int qw = q0 + w * 32;

  __shared__ f16 Kb[2][4096];  // [kv=64][dh=64], granule swz g^(row&7)
  __shared__ f16 Vb[2][4096];  // [dh=64][kv=64], granule swz g^(row&7)

  // Q B-fragments: Q[q = qw + l31][dh = s*16 + xi*8 .. +7], s = 0..3
  const f16* qp = qb + ((size_t)bh * 1024 + qw + l31) * 64 + xi * 8;
  f16x8 qf[4];
#pragma unroll
  for (int s = 0; s < 4; ++s)
    qf[s] = *reinterpret_cast<const f16x8*>(qp + s * 16);

  f32x16 O[2] = {};
  float mrun = -3.0e38f, rsum = 0.f;  // per-lane; q-row = qw + l31

  const f16* kbase = kb + (size_t)bh * 65536;
  const f16* vbase = vtb + (size_t)bh * 65536;
  // bias: S[c][4g+e] needs bias[q][t*64 + c*32 + 8g + 4*xi + e]
  const float* bq =
      bias + ((size_t)h * 1024 + qw + l31) * 1024 + 4 * xi;

  // DMA staging (identical to v16): 512 chunks of 16B per tile.
  auto stage = [&](int t, int nxt) {
#pragma unroll
    for (int i = 0; i < 2; ++i) {
      int c = (i * 4 + w) * 64 + l;
      int row = c >> 3, g = (c & 7) ^ (row & 7);
      LOADLDS16(kbase + (size_t)(t * 64 + row) * 64 + g * 8,
                &Kb[nxt][(i * 4 + w) * 512]);
      LOADLDS16(vbase + (size_t)row * 1024 + t * 64 + g * 8,
                &Vb[nxt][(i * 4 + w) * 512]);
    }
  };

  stage(0, 0);

#pragma unroll 1
  for (int t = 0; t < 16; ++t) {
    const int cur = t & 1;
    __builtin_amdgcn_s_barrier();
    // ---- bias loads FIRST (older than stage(t+1) in the VM queue) ----
    f32x4 bf[2][4];
#pragma unroll
    for (int c = 0; c < 2; ++c)
#pragma unroll
      for (int g = 0; g < 4; ++g)
        bf[c][g] = *reinterpret_cast<const f32x4*>(bq + t * 64 + c * 32 + 8 * g);
    __builtin_amdgcn_sched_barrier(0);
    if (t < 15) stage(t + 1, cur ^ 1);
    __builtin_amdgcn_sched_barrier(0);
    // drain ONLY stage(t): outstanding = 4(stage t) + 8(bias) + 4(stage t+1)
    if (t < 15) {
      asm volatile("s_waitcnt vmcnt(12)" ::: "memory");
    } else {
      asm volatile("s_waitcnt vmcnt(8)" ::: "memory");
    }
    __builtin_amdgcn_sched_barrier(0);

    // ---- S^T = K Q^T + bias  (S[c]: col q, rows kv = c*32 + pattern) ----
    f32x16 S[2];
#pragma unroll
    for (int c = 0; c < 2; ++c) {
#pragma unroll
      for (int g = 0; g < 4; ++g)
#pragma unroll
        for (int e = 0; e < 4; ++e) S[c][4 * g + e] = bf[c][g][e];
    }
    __builtin_amdgcn_s_setprio(1);
#pragma unroll
    for (int c = 0; c < 2; ++c) {
      int row = c * 32 + l31, s7 = l31 & 7;
      const f16* kbp = &Kb[cur][row * 64];
#pragma unroll
      for (int s = 0; s < 4; ++s) {
        f16x8 kf = *reinterpret_cast<const f16x8*>(kbp + (((2 * s + xi) ^ s7) * 8));
        S[c] = __builtin_amdgcn_mfma_f32_32x32x16_f16(kf, qf[s], S[c], 0, 0, 0);
      }
    }
    __builtin_amdgcn_s_setprio(0);

    // ---- defer-max (T13): all 32 S-values belong to one q-row ----
    float tmax = -3.0e38f;
#pragma unroll
    for (int c = 0; c < 2; ++c)
#pragma unroll
      for (int r = 0; r < 16; ++r) tmax = fmaxf(tmax, S[c][r]);
    if (!__all(tmax <= mrun + 8.0f)) {
      tmax = fmaxf(tmax, __shfl_xor(tmax, 32, 64));
      float mnew = fmaxf(mrun, tmax);
      float sc = __expf(mrun - mnew);  // identical in lanes l, l^32
      mrun = mnew;
      rsum *= sc;
#pragma unroll
      for (int d = 0; d < 2; ++d)
#pragma unroll
        for (int r = 0; r < 16; ++r) O[d][r] *= sc;
    }

    // ---- P = exp(S - m); per-lane rsum; pack quads ----
    f16x4 qd[2][4];
#pragma unroll
    for (int c = 0; c < 2; ++c)
#pragma unroll
      for (int g = 0; g < 4; ++g) {
        f32x4 p;
#pragma unroll
        for (int e = 0; e < 4; ++e) p[e] = __expf(S[c][4 * g + e] - mrun);
        rsum += (p[0] + p[1]) + (p[2] + p[3]);
        f16x4 ph = {(f16)p[0], (f16)p[1], (f16)p[2], (f16)p[3]};
        qd[c][g] = ph;
      }

    // ---- quad exchange with lane^32: build pb[u], u = 2c+v ----
    // lane xi==0 sends qd[c][2v+1], receives partner's qd[c][2v];
    // lane xi==1 sends qd[c][2v],   receives partner's qd[c][2v+1].
    f16x8 pb[4];
#pragma unroll
    for (int c = 0; c < 2; ++c)
#pragma unroll
      for (int v = 0; v < 2; ++v) {
        union { f16x4 h; unsigned int u[2]; } snd, rcv;
        snd.h = xi ? qd[c][2 * v] : qd[c][2 * v + 1];
        rcv.u[0] = __shfl_xor(snd.u[0], 32, 64);
        rcv.u[1] = __shfl_xor(snd.u[1], 32, 64);
        f16x4 own = xi ? qd[c][2 * v + 1] : qd[c][2 * v];
        f16x4 q1 = xi ? rcv.h : own;   // k-slots j=0..3
        f16x4 q2 = xi ? own : rcv.h;   // k-slots j=4..7
        f16x8 t8;
#pragma unroll
        for (int j = 0; j < 4; ++j) {
          t8[j] = q1[j];
          t8[4 + j] = q2[j];
        }
        pb[2 * c + v] = t8;
      }

    // ---- O^T += V^T P^T (A = V^T rows dh, B = pb rows q) ----
    __builtin_amdgcn_s_setprio(1);
#pragma unroll
    for (int d = 0; d < 2; ++d) {
      int row = d * 32 + l31, s7 = l31 & 7;
      const f16* vbp = &Vb[cur][row * 64];
#pragma unroll
      for (int u = 0; u < 4; ++u) {
        f16x8 vf = *reinterpret_cast<const f16x8*>(vbp + (((2 * u + xi) ^ s7) * 8));
        O[d] = __builtin_amdgcn_mfma_f32_32x32x16_f16(vf, pb[u], O[d], 0, 0, 0);
      }
    }
    __builtin_amdgcn_s_setprio(0);
    __builtin_amdgcn_sched_barrier(0);
  }

  // ---- final sum: lanes l and l^32 hold disjoint kv-halves of q ----
  rsum += __shfl_xor(rsum, 32, 64);
  float inv = 1.0f / rsum;

  // ---- epilogue: ctx[b][q][h*64+dh]; O[d] reg 4g+e -> dh = d*32+8g+4xi+e ----
  const int q = qw + l31;
  f16* cp = ctx + ((size_t)b * 1024 + q) * 1024 + h * 64;
#pragma unroll
  for (int d = 0; d < 2; ++d)
#pragma unroll
    for (int g = 0; g < 4; ++g) {
      f16x4 v4;
#pragma unroll
      for (int e = 0; e < 4; ++e) v4[e] = (f16)(O[d][4 * g + e] * inv);
      *reinterpret_cast<f16x4*>(cp + d * 32 + 8 * g + 4 * xi) = v4;
    }
}

// ---------------------------------------------------------------------------
extern "C" void kernel_launch(void* const* d_in, const int* in_sizes, int n_in,
                              void* d_out, int out_size, void* d_ws,
                              size_t ws_size, hipStream_t stream) {
  const float* input_ids = (const float*)d_in[0];
  const float* enc = (const float*)d_in[1];
  const float* bias = (const float*)d_in[2];
  const float* Wq = (const float*)d_in[3];
  const float* Wk = (const float*)d_in[4];
  const float* Wv = (const float*)d_in[5];
  const float* Wo = (const float*)d_in[6];

  char* ws = (char*)d_ws;
  const size_t MB = 1024 * 1024;
  f16* Xq  = (f16*)(ws + 0 * MB);   // 8 MB; dead after QKV-proj -> reused as ctx
  f16* Xkv = (f16*)(ws + 8 * MB);   // 8 MB (GEMM A input)
  f16* Wqt = (f16*)(ws + 16 * MB);  // 2 MB each; Wqt|Wkt|Wvt contiguous = [3072][1024]
  f16* Wkt = (f16*)(ws + 18 * MB);
  f16* Wvt = (f16*)(ws + 20 * MB);
  f16* Wot = (f16*)(ws + 22 * MB);
  f16* qbuf = (f16*)(ws + 24 * MB); // 8 MB [bh][s][dh]; kbuf plane follows;
  f16* kbuf = (f16*)(ws + 32 * MB); // plane 2 = vtb [bh][dh][s] (transposed in epi)
  f16* vtb  = (f16*)(ws + 40 * MB);
  f16* ctxb = Xq;   // [4096][1024]

  // merged cast + weight-transpose prep (one launch)
  k_prep<<<9216, 256, 0, stream>>>(input_ids, enc, Xq, Xkv, Wq, Wk, Wv, Wo,
                                   Wqt, Wkt, Wvt, Wot);

  // fused Q+K+V projection (Q/K planes swapped-operand, V transposed in epi)
  k_gemm_qkv<<<dim3(24, 32), 256, 0, stream>>>(Xq, Xkv, Wqt, qbuf);

  k_attn<<<512, 256, 0, stream>>>(qbuf, kbuf, vtb, bias, ctxb);

  k_gemm_o<<<dim3(8, 64), 256, 0, stream>>>(ctxb, Wot, (float*)d_out, 4096, 1024, 1024);
}